// Round 1
// baseline (1240.109 us; speedup 1.0000x reference)
//
#include <hip/hip_runtime.h>
#include <cstdint>

#define BB 4096
#define NV 20
#define CC 512
#define HH 256   // hidden
#define NC 40    // classes
#define SV 8     // selected views

// ---------------------------------------------------------------------------
// Pre-kernel 1: pooled mean per batch, in f64 (decision path) and f32 (fast path)
// ---------------------------------------------------------------------------
__global__ void pooled_kernel(const float* __restrict__ F0,
                              double* __restrict__ pd, float* __restrict__ pf) {
    int b = blockIdx.x;
    int j = threadIdx.x;
    const float* X = F0 + (size_t)b * (NV * CC);
    for (int c = j; c < CC; c += 256) {
        double s = 0.0;
#pragma unroll
        for (int r = 0; r < NV; ++r) s += (double)X[r * CC + c];
        s = s / (double)NV;
        pd[(size_t)b * CC + c] = s;
        pf[(size_t)b * CC + c] = (float)s;
    }
}

// ---------------------------------------------------------------------------
// Pre-kernel 2: transpose W2 [256,40] -> W2T [40,256] for contiguous reads
// ---------------------------------------------------------------------------
__global__ void w2t_kernel(const float* __restrict__ W2, float* __restrict__ W2T) {
    int t = blockIdx.x * 256 + threadIdx.x;
    if (t < HH * NC) {
        int cls = t / HH;
        int k = t - cls * HH;
        W2T[cls * HH + k] = W2[k * NC + cls];
    }
}

// ---------------------------------------------------------------------------
// Main fused kernel: one block per batch
// ---------------------------------------------------------------------------
__global__ __launch_bounds__(256) void main_kernel(
    const float* __restrict__ F0, const float* __restrict__ V0,
    const float* __restrict__ W1, const float* __restrict__ b1,
    const float* __restrict__ W2, const float* __restrict__ b2,
    const double* __restrict__ pd, const float* __restrict__ pf,
    const float* __restrict__ W2T,
    float* __restrict__ outF, float* __restrict__ outS, float* __restrict__ outV)
{
    const int b = blockIdx.x;
    const int j = threadIdx.x;

    __shared__ float  Hl[(NV + 1) * HH];   // hidden activations, 21 rows
    __shared__ float  Sc[(NV + 1) * NC];   // scores, 21 rows x 40
    __shared__ double Dbuf[HH];            // f64 scratch / reduction
    __shared__ double Sd[NC];              // f64 pooled scores (fixup)
    __shared__ double SFd[NV];             // f64 score_F (fixup)
    __shared__ int    idx8[SV];
    __shared__ int    flags[2];            // [0]=pred fixup, [1]=topk fixup
    __shared__ int    predSh;

    const size_t xb = (size_t)b * (NV * CC);
    const float* Xb = F0 + xb;
    const float* Pb = pf + (size_t)b * CC;

    // ---------------- layer 1: h[r][j] = sum_c X[r][c] * W1[c][j] ----------
    float acc[NV + 1];
#pragma unroll
    for (int r = 0; r <= NV; ++r) acc[r] = 0.f;

    for (int c = 0; c < CC; c += 4) {
        float w0 = W1[(c + 0) * HH + j];
        float w1v = W1[(c + 1) * HH + j];
        float w2v = W1[(c + 2) * HH + j];
        float w3v = W1[(c + 3) * HH + j];
#pragma unroll
        for (int r = 0; r < NV; ++r) {
            acc[r] = fmaf(Xb[r * CC + c + 0], w0, acc[r]);
            acc[r] = fmaf(Xb[r * CC + c + 1], w1v, acc[r]);
            acc[r] = fmaf(Xb[r * CC + c + 2], w2v, acc[r]);
            acc[r] = fmaf(Xb[r * CC + c + 3], w3v, acc[r]);
        }
        acc[NV] = fmaf(Pb[c + 0], w0, acc[NV]);
        acc[NV] = fmaf(Pb[c + 1], w1v, acc[NV]);
        acc[NV] = fmaf(Pb[c + 2], w2v, acc[NV]);
        acc[NV] = fmaf(Pb[c + 3], w3v, acc[NV]);
    }

    {
        float bj = b1[j];
#pragma unroll
        for (int r = 0; r <= NV; ++r) {
            float h = acc[r] + bj;
            h = (h > 0.f) ? h : 0.2f * h;
            Hl[r * HH + j] = h;
        }
    }
    __syncthreads();

    // ---------------- layer 2: scores[r][cls] --------------------------------
    for (int o = j; o < (NV + 1) * NC; o += 256) {
        int r = o / NC;
        int cls = o - r * NC;
        const float* hrow = &Hl[r * HH];
        const float* wcol = &W2T[cls * HH];
        float s = 0.f;
        for (int k = 0; k < HH; k += 4) {
            s = fmaf(hrow[k + 0], wcol[k + 0], s);
            s = fmaf(hrow[k + 1], wcol[k + 1], s);
            s = fmaf(hrow[k + 2], wcol[k + 2], s);
            s = fmaf(hrow[k + 3], wcol[k + 3], s);
        }
        Sc[o] = s + b2[cls];
    }
    __syncthreads();

    // ---------------- pred = argmax of pooled scores (+gap check) -----------
    if (j == 0) {
        const float* sp = &Sc[NV * NC];
        int p = 0;
        float m1 = sp[0];
        for (int c = 1; c < NC; ++c)
            if (sp[c] > m1) { m1 = sp[c]; p = c; }
        float m2 = -1e30f;
        for (int c = 0; c < NC; ++c)
            if (c != p && sp[c] > m2) m2 = sp[c];
        flags[0] = (m1 - m2 < 1e-4f) ? 1 : 0;
        predSh = p;
    }
    __syncthreads();

    if (flags[0]) {  // rare: f64 rescore of pooled row
        const double* pdb = pd + (size_t)b * CC;
        double a = 0.0;
        for (int c = 0; c < CC; ++c) a += pdb[c] * (double)W1[c * HH + j];
        double h = a + (double)b1[j];
        h = (h > 0.0) ? h : 0.2 * h;
        Dbuf[j] = h;
        __syncthreads();
        if (j < NC) {
            double s = 0.0;
            for (int k = 0; k < HH; ++k) s += Dbuf[k] * (double)W2[k * NC + j];
            Sd[j] = s + (double)b2[j];
        }
        __syncthreads();
        if (j == 0) {
            int p = 0;
            double m = Sd[0];
            for (int c = 1; c < NC; ++c)
                if (Sd[c] > m) { m = Sd[c]; p = c; }
            predSh = p;
        }
        __syncthreads();
    }

    // ---------------- top-8 selection on score_F (+gap check) ---------------
    if (j == 0) {
        int p = predSh;
        float v[NV];
#pragma unroll
        for (int n = 0; n < NV; ++n) v[n] = Sc[n * NC + p];
        int ord[9];
        float vals[9];
        unsigned taken = 0;
#pragma unroll
        for (int s = 0; s < 9; ++s) {
            int bi = 0;
            float bv = -1e30f;
#pragma unroll
            for (int n = 0; n < NV; ++n)
                if (!((taken >> n) & 1u) && v[n] > bv) { bv = v[n]; bi = n; }
            taken |= 1u << bi;
            ord[s] = bi;
            vals[s] = bv;
        }
        int fix = 0;
#pragma unroll
        for (int s = 0; s < 8; ++s)
            if (vals[s] - vals[s + 1] < 1e-4f) fix = 1;
        flags[1] = fix;
        if (!fix)
#pragma unroll
            for (int s = 0; s < SV; ++s) idx8[s] = ord[s];
    }
    __syncthreads();

    if (flags[1]) {  // rare: full f64 rescore of all 20 view scores at column pred
        int p = predSh;
        for (int r = 0; r < NV; ++r) {
            double a = 0.0;
            for (int c = 0; c < CC; ++c)
                a += (double)Xb[r * CC + c] * (double)W1[c * HH + j];
            double h = a + (double)b1[j];
            h = (h > 0.0) ? h : 0.2 * h;
            Dbuf[j] = h * (double)W2[j * NC + p];
            __syncthreads();
            for (int off = 128; off >= 1; off >>= 1) {
                if (j < off) Dbuf[j] += Dbuf[j + off];
                __syncthreads();
            }
            if (j == 0) SFd[r] = Dbuf[0] + (double)b2[p];
            __syncthreads();
        }
        if (j == 0) {
            unsigned taken = 0;
            for (int s = 0; s < SV; ++s) {
                int bi = 0;
                double bv = -1e300;
                for (int n = 0; n < NV; ++n)
                    if (!((taken >> n) & 1u) && SFd[n] > bv) { bv = SFd[n]; bi = n; }
                taken |= 1u << bi;
                idx8[s] = bi;
            }
        }
        __syncthreads();
    }

    // ---------------- epilogue: write score, F_new, vertices_new ------------
    for (int t = j; t < NV * NC; t += 256)
        outS[(size_t)b * (NV * NC) + t] = Sc[t];

#pragma unroll
    for (int s = 0; s < SV; ++s) {
        int row = idx8[s];
        const float* src = Xb + row * CC;
        float* dst = outF + ((size_t)b * SV + s) * CC;
        for (int t = j; t < CC; t += 256) dst[t] = src[t];
    }

    if (j < SV * 3) {
        int s = j / 3;
        int d = j - s * 3;
        outV[((size_t)b * SV + s) * 3 + d] = V0[((size_t)b * NV + idx8[s]) * 3 + d];
    }
}

// ---------------------------------------------------------------------------
extern "C" void kernel_launch(void* const* d_in, const int* in_sizes, int n_in,
                              void* d_out, int out_size, void* d_ws, size_t ws_size,
                              hipStream_t stream) {
    const float* F0 = (const float*)d_in[0];
    const float* V0 = (const float*)d_in[1];
    const float* W1 = (const float*)d_in[2];
    const float* b1 = (const float*)d_in[3];
    const float* W2 = (const float*)d_in[4];
    const float* b2 = (const float*)d_in[5];
    // d_in[6] = k (==8), compile-time constant SV

    char* ws = (char*)d_ws;
    double* pd = (double*)ws;                                     // 4096*512*8  = 16 MiB
    float* pf = (float*)(ws + (size_t)BB * CC * 8);               // 4096*512*4  = 8 MiB
    float* W2T = (float*)(ws + (size_t)BB * CC * 8 + (size_t)BB * CC * 4);  // 40 KiB

    float* out = (float*)d_out;
    float* outF = out;                                // [4096,8,512]
    float* outS = out + (size_t)BB * SV * CC;         // [4096,20,40]
    float* outV = outS + (size_t)BB * NV * NC;        // [4096,8,3]

    pooled_kernel<<<BB, 256, 0, stream>>>(F0, pd, pf);
    w2t_kernel<<<(HH * NC + 255) / 256, 256, 0, stream>>>(W2, W2T);
    main_kernel<<<BB, 256, 0, stream>>>(F0, V0, W1, b1, W2, b2, pd, pf, W2T,
                                        outF, outS, outV);
}

// Round 2
// 1218.805 us; speedup vs baseline: 1.0175x; 1.0175x over previous
//
#include <hip/hip_runtime.h>
#include <cstdint>

#define BB 4096
#define NV 20
#define CC 512
#define HH 256   // hidden
#define NC 40    // classes
#define SV 8     // selected views

// One block per batch, fully fused.
// LDS plan (single 43008-B buffer, phase-aliased):
//   phase A (staging + layer1): Xs[21][512] f32  (rows 0-19 = views, row 20 = pooled)
//   phase B (after layer1):     Hl[21][256] @0, Sc[21][40] @5376f,
//                               pooledD[512] f64 @6216f, Dbuf[256] f64 @7240f,
//                               Sd[40] f64 @7752f, SFd[20] f64 @7832f
__global__ __launch_bounds__(256) void fused_kernel(
    const float* __restrict__ F0, const float* __restrict__ V0,
    const float* __restrict__ W1, const float* __restrict__ b1,
    const float* __restrict__ W2, const float* __restrict__ b2,
    float* __restrict__ outF, float* __restrict__ outS, float* __restrict__ outV)
{
    const int b = blockIdx.x;
    const int j = threadIdx.x;

    __shared__ float Xs[(NV + 1) * CC];   // 43008 B
    __shared__ int   idx8[SV];
    __shared__ int   flags[2];
    __shared__ int   predSh;

    float*  Hl      = Xs;                                   // 21*256 floats
    float*  Sc      = Xs + (NV + 1) * HH;                   // 840 floats, byte 21504
    double* pooledD = (double*)&Xs[6216];                   // byte 24864, 512 dbl
    double* Dbuf    = (double*)&Xs[7240];                   // byte 28960, 256 dbl
    double* Sd      = (double*)&Xs[7752];                   // byte 31008, 40 dbl
    double* SFd     = (double*)&Xs[7832];                   // byte 31328, 20 dbl

    const float* Xb = F0 + (size_t)b * (NV * CC);

    // ---------------- stage X into LDS (coalesced float4) -------------------
    {
        const float4* src = (const float4*)Xb;
        float4* dst = (float4*)Xs;
        for (int t = j; t < NV * CC / 4; t += 256) dst[t] = src[t];
    }
    __syncthreads();

    // ---------------- pooled row (row 20), f32 fast path --------------------
    for (int c = j; c < CC; c += 256) {
        float s = 0.f;
#pragma unroll
        for (int r = 0; r < NV; ++r) s += Xs[r * CC + c];
        Xs[NV * CC + c] = s * (1.0f / NV);
    }
    __syncthreads();

    // ---------------- layer 1: h[r][j] = sum_c X[r][c] * W1[c][j] -----------
    float acc[NV + 1];
#pragma unroll
    for (int r = 0; r <= NV; ++r) acc[r] = 0.f;

    const float4* XsV = (const float4*)Xs;
    {
        // W1 column loads: coalesced dwords, software-prefetched one c4 ahead.
        float w0 = W1[0 * HH + j];
        float w1v = W1[1 * HH + j];
        float w2v = W1[2 * HH + j];
        float w3v = W1[3 * HH + j];
        for (int c4 = 0; c4 < CC / 4; ++c4) {
            int cn = (c4 + 1 < CC / 4) ? (c4 + 1) : c4;   // clamp: harmless re-read
            const float* Wn = W1 + cn * 4 * HH + j;
            float n0 = Wn[0];
            float n1 = Wn[HH];
            float n2 = Wn[2 * HH];
            float n3 = Wn[3 * HH];
#pragma unroll
            for (int r = 0; r <= NV; ++r) {
                float4 x = XsV[r * (CC / 4) + c4];   // wave-uniform addr -> LDS broadcast
                acc[r] = fmaf(x.x, w0, acc[r]);
                acc[r] = fmaf(x.y, w1v, acc[r]);
                acc[r] = fmaf(x.z, w2v, acc[r]);
                acc[r] = fmaf(x.w, w3v, acc[r]);
            }
            w0 = n0; w1v = n1; w2v = n2; w3v = n3;
        }
    }
    __syncthreads();   // all waves done READING Xs before Hl overwrites it

    {
        float bj = b1[j];
#pragma unroll
        for (int r = 0; r <= NV; ++r) {
            float h = acc[r] + bj;
            Hl[r * HH + j] = (h > 0.f) ? h : 0.2f * h;
        }
    }
    __syncthreads();

    // ---------------- layer 2: Sc[r][cls], W2 read direct (coalesced) -------
    for (int o = j; o < (NV + 1) * NC; o += 256) {
        int r = o / NC;
        int cls = o - r * NC;
        const float* hrow = &Hl[r * HH];
        float s = 0.f;
        for (int k = 0; k < HH; k += 4) {
            s = fmaf(hrow[k + 0], W2[(k + 0) * NC + cls], s);
            s = fmaf(hrow[k + 1], W2[(k + 1) * NC + cls], s);
            s = fmaf(hrow[k + 2], W2[(k + 2) * NC + cls], s);
            s = fmaf(hrow[k + 3], W2[(k + 3) * NC + cls], s);
        }
        Sc[o] = s + b2[cls];
    }
    __syncthreads();

    // ---------------- pred = argmax of pooled scores (+gap check) -----------
    if (j == 0) {
        const float* sp = &Sc[NV * NC];
        int p = 0;
        float m1 = sp[0];
        for (int c = 1; c < NC; ++c)
            if (sp[c] > m1) { m1 = sp[c]; p = c; }
        float m2 = -1e30f;
        for (int c = 0; c < NC; ++c)
            if (c != p && sp[c] > m2) m2 = sp[c];
        flags[0] = (m1 - m2 < 1e-4f) ? 1 : 0;
        predSh = p;
    }
    __syncthreads();

    if (flags[0]) {  // rare: f64 rescore of pooled row (same math/order as before)
        for (int c = j; c < CC; c += 256) {
            double s = 0.0;
            for (int r = 0; r < NV; ++r) s += (double)Xb[r * CC + c];
            pooledD[c] = s / (double)NV;
        }
        __syncthreads();
        double a = 0.0;
        for (int c = 0; c < CC; ++c) a += pooledD[c] * (double)W1[c * HH + j];
        double h = a + (double)b1[j];
        h = (h > 0.0) ? h : 0.2 * h;
        Dbuf[j] = h;
        __syncthreads();
        if (j < NC) {
            double s = 0.0;
            for (int k = 0; k < HH; ++k) s += Dbuf[k] * (double)W2[k * NC + j];
            Sd[j] = s + (double)b2[j];
        }
        __syncthreads();
        if (j == 0) {
            int p = 0;
            double m = Sd[0];
            for (int c = 1; c < NC; ++c)
                if (Sd[c] > m) { m = Sd[c]; p = c; }
            predSh = p;
        }
        __syncthreads();
    }

    // ---------------- top-8 selection on score_F (+gap check) ---------------
    if (j == 0) {
        int p = predSh;
        float v[NV];
#pragma unroll
        for (int n = 0; n < NV; ++n) v[n] = Sc[n * NC + p];
        int ord[9];
        float vals[9];
        unsigned taken = 0;
#pragma unroll
        for (int s = 0; s < 9; ++s) {
            int bi = 0;
            float bv = -1e30f;
#pragma unroll
            for (int n = 0; n < NV; ++n)
                if (!((taken >> n) & 1u) && v[n] > bv) { bv = v[n]; bi = n; }
            taken |= 1u << bi;
            ord[s] = bi;
            vals[s] = bv;
        }
        int fix = 0;
#pragma unroll
        for (int s = 0; s < 8; ++s)
            if (vals[s] - vals[s + 1] < 1e-4f) fix = 1;
        flags[1] = fix;
        if (!fix)
#pragma unroll
            for (int s = 0; s < SV; ++s) idx8[s] = ord[s];
    }
    __syncthreads();

    if (flags[1]) {  // rare: full f64 rescore of all 20 view scores at column pred
        int p = predSh;
        for (int r = 0; r < NV; ++r) {
            double a = 0.0;
            for (int c = 0; c < CC; ++c)
                a += (double)Xb[r * CC + c] * (double)W1[c * HH + j];
            double h = a + (double)b1[j];
            h = (h > 0.0) ? h : 0.2 * h;
            Dbuf[j] = h * (double)W2[j * NC + p];
            __syncthreads();
            for (int off = 128; off >= 1; off >>= 1) {
                if (j < off) Dbuf[j] += Dbuf[j + off];
                __syncthreads();
            }
            if (j == 0) SFd[r] = Dbuf[0] + (double)b2[p];
            __syncthreads();
        }
        if (j == 0) {
            unsigned taken = 0;
            for (int s = 0; s < SV; ++s) {
                int bi = 0;
                double bv = -1e300;
                for (int n = 0; n < NV; ++n)
                    if (!((taken >> n) & 1u) && SFd[n] > bv) { bv = SFd[n]; bi = n; }
                taken |= 1u << bi;
                idx8[s] = bi;
            }
        }
        __syncthreads();
    }

    // ---------------- epilogue: score, F_new (float4 gather), vertices ------
    for (int t = j; t < NV * NC; t += 256)
        outS[(size_t)b * (NV * NC) + t] = Sc[t];

    for (int q = j; q < SV * (CC / 4); q += 256) {
        int s = q >> 7;            // CC/4 == 128
        int t4 = q & 127;
        const float4* src = (const float4*)(Xb + idx8[s] * CC);
        float4* dst = (float4*)(outF + ((size_t)b * SV + s) * CC);
        dst[t4] = src[t4];
    }

    if (j < SV * 3) {
        int s = j / 3;
        int d = j - s * 3;
        outV[((size_t)b * SV + s) * 3 + d] = V0[((size_t)b * NV + idx8[s]) * 3 + d];
    }
}

// ---------------------------------------------------------------------------
extern "C" void kernel_launch(void* const* d_in, const int* in_sizes, int n_in,
                              void* d_out, int out_size, void* d_ws, size_t ws_size,
                              hipStream_t stream) {
    const float* F0 = (const float*)d_in[0];
    const float* V0 = (const float*)d_in[1];
    const float* W1 = (const float*)d_in[2];
    const float* b1 = (const float*)d_in[3];
    const float* W2 = (const float*)d_in[4];
    const float* b2 = (const float*)d_in[5];
    // d_in[6] = k (==8), compile-time constant SV

    float* out = (float*)d_out;
    float* outF = out;                                // [4096,8,512]
    float* outS = out + (size_t)BB * SV * CC;         // [4096,20,40]
    float* outV = outS + (size_t)BB * NV * NC;        // [4096,8,3]

    fused_kernel<<<BB, 256, 0, stream>>>(F0, V0, W1, b1, W2, b2, outF, outS, outV);
}

// Round 3
// 1120.911 us; speedup vs baseline: 1.1063x; 1.0873x over previous
//
#include <hip/hip_runtime.h>
#include <cstdint>

#define BB 4096
#define NV 20
#define CC 512
#define HH 256   // hidden
#define NC 40    // classes
#define SV 8     // selected views

// X LDS layout (swizzled, float4 units): row stride 132, quarter offset 33.
//   float4 index: Vidx4(r, v) = r*132 + 33*(v>>5) + (v&31),  v = c/4 in [0,128)
//   float  index: Fidx (r, c) = r*528 + 132*(c>>7) + (c&127)
// Quarter q reads float4s at r*132 + 33q + c4 -> the 4 quarter addresses hit
// disjoint bank groups (132q mod 32 = 4q) -> conflict-free broadcasts.
#define RS4 132
#define RSF 528

__global__ __launch_bounds__(256) void fused_kernel(
    const float* __restrict__ F0, const float* __restrict__ V0,
    const float* __restrict__ W1, const float* __restrict__ b1,
    const float* __restrict__ W2, const float* __restrict__ b2,
    float* __restrict__ outF, float* __restrict__ outS, float* __restrict__ outV)
{
    const int b = blockIdx.x;
    const int j = threadIdx.x;

    __shared__ __align__(16) float Xs[(NV + 1) * RSF];   // 44352 B, phase-aliased
    __shared__ int   idx8[SV];
    __shared__ int   flags[2];
    __shared__ int   predSh;

    float*  Hl      = Xs;                    // phase B: 21*256 floats
    float*  Sc      = Xs + (NV + 1) * HH;    // 840 floats @5376
    double* pooledD = (double*)&Xs[6216];    // 512 dbl (byte 24864, 8-aligned)
    double* Dbuf    = (double*)&Xs[7240];    // 256 dbl
    double* Sd      = (double*)&Xs[7752];    // 40 dbl
    double* SFd     = (double*)&Xs[7832];    // 20 dbl, ends @7872 < 11088

    const float* Xb = F0 + (size_t)b * (NV * CC);

    // ---------------- stage X into LDS (coalesced float4, swizzled store) ---
    {
        const float4* src = (const float4*)Xb;
        float4* dst = (float4*)Xs;
        for (int t = j; t < NV * (CC / 4); t += 256) {
            int r = t >> 7;
            int v = t & 127;
            dst[r * RS4 + 33 * (v >> 5) + (v & 31)] = src[t];
        }
    }
    __syncthreads();

    // ---------------- pooled row (r=20), f32, same order as before ----------
    for (int c = j; c < CC; c += 256) {
        int cb = 132 * (c >> 7) + (c & 127);
        float s = 0.f;
#pragma unroll
        for (int r = 0; r < NV; ++r) s += Xs[r * RSF + cb];
        Xs[NV * RSF + cb] = s * (1.0f / NV);
    }
    __syncthreads();

    // ---------------- layer 1: K-split x column-quad -------------------------
    // thread: cg = j>>2 owns columns 4cg..4cg+3; q = j&3 owns c in [128q,128q+128)
    const int cg = j >> 2;
    const int q  = j & 3;

    float4 acc[NV + 1];
#pragma unroll
    for (int r = 0; r <= NV; ++r) acc[r] = make_float4(0.f, 0.f, 0.f, 0.f);

    const float4* XsV = (const float4*)Xs;
    const float4* Wp  = (const float4*)W1;   // [512 rows][64 float4]
    {
        const int crow0 = q * 128;
        float4 w0 = Wp[(crow0 + 0) * 64 + cg];
        float4 w1 = Wp[(crow0 + 1) * 64 + cg];
        float4 w2 = Wp[(crow0 + 2) * 64 + cg];
        float4 w3 = Wp[(crow0 + 3) * 64 + cg];
        for (int c4 = 0; c4 < 32; ++c4) {
            int nc4 = (c4 + 1 < 32) ? c4 + 1 : c4;        // clamp: harmless re-read
            int nrow = crow0 + nc4 * 4;
            float4 n0 = Wp[(nrow + 0) * 64 + cg];
            float4 n1 = Wp[(nrow + 1) * 64 + cg];
            float4 n2 = Wp[(nrow + 2) * 64 + cg];
            float4 n3 = Wp[(nrow + 3) * 64 + cg];
            const int off = q * 33 + c4;
#pragma unroll
            for (int r = 0; r <= NV; ++r) {
                float4 x = XsV[r * RS4 + off];
                float4 a = acc[r];
                a.x = fmaf(x.x, w0.x, a.x); a.y = fmaf(x.x, w0.y, a.y);
                a.z = fmaf(x.x, w0.z, a.z); a.w = fmaf(x.x, w0.w, a.w);
                a.x = fmaf(x.y, w1.x, a.x); a.y = fmaf(x.y, w1.y, a.y);
                a.z = fmaf(x.y, w1.z, a.z); a.w = fmaf(x.y, w1.w, a.w);
                a.x = fmaf(x.z, w2.x, a.x); a.y = fmaf(x.z, w2.y, a.y);
                a.z = fmaf(x.z, w2.z, a.z); a.w = fmaf(x.z, w2.w, a.w);
                a.x = fmaf(x.w, w3.x, a.x); a.y = fmaf(x.w, w3.y, a.y);
                a.z = fmaf(x.w, w3.z, a.z); a.w = fmaf(x.w, w3.w, a.w);
                acc[r] = a;
            }
            w0 = n0; w1 = n1; w2 = n2; w3 = n3;
        }
    }
    __syncthreads();   // all waves done READING Xs before Hl overwrites it

    // quad reduce (lanes 4m..4m+3, same wave), bias, LeakyReLU, write Hl
    {
        const int col = (cg << 2) + q;
        const float bcol = b1[col];
#pragma unroll
        for (int r = 0; r <= NV; ++r) {
            float4 a = acc[r];
            a.x += __shfl_xor(a.x, 1); a.y += __shfl_xor(a.y, 1);
            a.z += __shfl_xor(a.z, 1); a.w += __shfl_xor(a.w, 1);
            a.x += __shfl_xor(a.x, 2); a.y += __shfl_xor(a.y, 2);
            a.z += __shfl_xor(a.z, 2); a.w += __shfl_xor(a.w, 2);
            float h = (q == 0) ? a.x : (q == 1) ? a.y : (q == 2) ? a.z : a.w;
            h += bcol;
            Hl[r * HH + col] = (h > 0.f) ? h : 0.2f * h;
        }
    }
    __syncthreads();

    // ---------------- layer 2: Sc[r][cls], W2 read direct (coalesced) -------
    for (int o = j; o < (NV + 1) * NC; o += 256) {
        int r = o / NC;
        int cls = o - r * NC;
        const float* hrow = &Hl[r * HH];
        float s = 0.f;
        for (int k = 0; k < HH; k += 4) {
            s = fmaf(hrow[k + 0], W2[(k + 0) * NC + cls], s);
            s = fmaf(hrow[k + 1], W2[(k + 1) * NC + cls], s);
            s = fmaf(hrow[k + 2], W2[(k + 2) * NC + cls], s);
            s = fmaf(hrow[k + 3], W2[(k + 3) * NC + cls], s);
        }
        Sc[o] = s + b2[cls];
    }
    __syncthreads();

    // ---------------- pred = argmax of pooled scores (+gap check) -----------
    if (j == 0) {
        const float* sp = &Sc[NV * NC];
        int p = 0;
        float m1 = sp[0];
        for (int c = 1; c < NC; ++c)
            if (sp[c] > m1) { m1 = sp[c]; p = c; }
        float m2 = -1e30f;
        for (int c = 0; c < NC; ++c)
            if (c != p && sp[c] > m2) m2 = sp[c];
        flags[0] = (m1 - m2 < 1e-4f) ? 1 : 0;
        predSh = p;
    }
    __syncthreads();

    if (flags[0]) {  // rare: f64 rescore of pooled row
        for (int c = j; c < CC; c += 256) {
            double s = 0.0;
            for (int r = 0; r < NV; ++r) s += (double)Xb[r * CC + c];
            pooledD[c] = s / (double)NV;
        }
        __syncthreads();
        double a = 0.0;
        for (int c = 0; c < CC; ++c) a += pooledD[c] * (double)W1[c * HH + j];
        double h = a + (double)b1[j];
        h = (h > 0.0) ? h : 0.2 * h;
        Dbuf[j] = h;
        __syncthreads();
        if (j < NC) {
            double s = 0.0;
            for (int k = 0; k < HH; ++k) s += Dbuf[k] * (double)W2[k * NC + j];
            Sd[j] = s + (double)b2[j];
        }
        __syncthreads();
        if (j == 0) {
            int p = 0;
            double m = Sd[0];
            for (int c = 1; c < NC; ++c)
                if (Sd[c] > m) { m = Sd[c]; p = c; }
            predSh = p;
        }
        __syncthreads();
    }

    // ---------------- top-8 selection on score_F (+gap check) ---------------
    if (j == 0) {
        int p = predSh;
        float v[NV];
#pragma unroll
        for (int n = 0; n < NV; ++n) v[n] = Sc[n * NC + p];
        int ord[9];
        float vals[9];
        unsigned taken = 0;
#pragma unroll
        for (int s = 0; s < 9; ++s) {
            int bi = 0;
            float bv = -1e30f;
#pragma unroll
            for (int n = 0; n < NV; ++n)
                if (!((taken >> n) & 1u) && v[n] > bv) { bv = v[n]; bi = n; }
            taken |= 1u << bi;
            ord[s] = bi;
            vals[s] = bv;
        }
        int fix = 0;
#pragma unroll
        for (int s = 0; s < 8; ++s)
            if (vals[s] - vals[s + 1] < 1e-4f) fix = 1;
        flags[1] = fix;
        if (!fix)
#pragma unroll
            for (int s = 0; s < SV; ++s) idx8[s] = ord[s];
    }
    __syncthreads();

    if (flags[1]) {  // rare: full f64 rescore of all 20 view scores at column pred
        int p = predSh;
        for (int r = 0; r < NV; ++r) {
            double a = 0.0;
            for (int c = 0; c < CC; ++c)
                a += (double)Xb[r * CC + c] * (double)W1[c * HH + j];
            double h = a + (double)b1[j];
            h = (h > 0.0) ? h : 0.2 * h;
            Dbuf[j] = h * (double)W2[j * NC + p];
            __syncthreads();
            for (int off = 128; off >= 1; off >>= 1) {
                if (j < off) Dbuf[j] += Dbuf[j + off];
                __syncthreads();
            }
            if (j == 0) SFd[r] = Dbuf[0] + (double)b2[p];
            __syncthreads();
        }
        if (j == 0) {
            unsigned taken = 0;
            for (int s = 0; s < SV; ++s) {
                int bi = 0;
                double bv = -1e300;
                for (int n = 0; n < NV; ++n)
                    if (!((taken >> n) & 1u) && SFd[n] > bv) { bv = SFd[n]; bi = n; }
                taken |= 1u << bi;
                idx8[s] = bi;
            }
        }
        __syncthreads();
    }

    // ---------------- epilogue: score, F_new (float4 gather), vertices ------
    for (int t = j; t < NV * NC; t += 256)
        outS[(size_t)b * (NV * NC) + t] = Sc[t];

    for (int qq = j; qq < SV * (CC / 4); qq += 256) {
        int s = qq >> 7;           // CC/4 == 128
        int t4 = qq & 127;
        const float4* src = (const float4*)(Xb + idx8[s] * CC);
        float4* dst = (float4*)(outF + ((size_t)b * SV + s) * CC);
        dst[t4] = src[t4];
    }

    if (j < SV * 3) {
        int s = j / 3;
        int d = j - s * 3;
        outV[((size_t)b * SV + s) * 3 + d] = V0[((size_t)b * NV + idx8[s]) * 3 + d];
    }
}

// ---------------------------------------------------------------------------
extern "C" void kernel_launch(void* const* d_in, const int* in_sizes, int n_in,
                              void* d_out, int out_size, void* d_ws, size_t ws_size,
                              hipStream_t stream) {
    const float* F0 = (const float*)d_in[0];
    const float* V0 = (const float*)d_in[1];
    const float* W1 = (const float*)d_in[2];
    const float* b1 = (const float*)d_in[3];
    const float* W2 = (const float*)d_in[4];
    const float* b2 = (const float*)d_in[5];
    // d_in[6] = k (==8), compile-time constant SV

    float* out = (float*)d_out;
    float* outF = out;                                // [4096,8,512]
    float* outS = out + (size_t)BB * SV * CC;         // [4096,20,40]
    float* outV = outS + (size_t)BB * NV * NC;        // [4096,8,3]

    fused_kernel<<<BB, 256, 0, stream>>>(F0, V0, W1, b1, W2, b2, outF, outS, outV);
}

// Round 4
// 828.520 us; speedup vs baseline: 1.4968x; 1.3529x over previous
//
#include <hip/hip_runtime.h>
#include <cstdint>

#define BB 4096
#define NV 20
#define CC 512
#define HH 256   // hidden
#define NC 40    // classes
#define SV 8     // selected views
#define TAU 2e-4f

typedef short short8 __attribute__((ext_vector_type(8)));
typedef float f32x4 __attribute__((ext_vector_type(4)));
typedef unsigned short ushort4v __attribute__((ext_vector_type(4)));

__device__ __forceinline__ unsigned short f2bf(float x) {
    unsigned u = __float_as_uint(x);
    unsigned r = (u + 0x7FFFu + ((u >> 16) & 1u)) >> 16;
    return (unsigned short)r;
}
__device__ __forceinline__ float bf2f(unsigned short h) {
    return __uint_as_float(((unsigned)h) << 16);
}

#define MFMA16(A, B, C) __builtin_amdgcn_mfma_f32_16x16x32_bf16(A, B, C, 0, 0, 0)
#define BC8(x) __builtin_bit_cast(short8, x)

// ---------------------------------------------------------------------------
// Pre-pack W1 [512][256] -> fragment-ordered bf16 hi/lo:
//   e = ((ks*256 + n)*4 + kq)*8 + j3 ; k = ks*32 + kq*8 + j3
// ---------------------------------------------------------------------------
__global__ void w1pack_kernel(const float* __restrict__ W1,
                              unsigned short* __restrict__ w1fh,
                              unsigned short* __restrict__ w1fl) {
    int e = blockIdx.x * 256 + threadIdx.x;           // 131072 total
    int j3 = e & 7, kq = (e >> 3) & 3, n = (e >> 5) & 255, ks = e >> 13;
    int k = ks * 32 + kq * 8 + j3;
    float x = W1[k * HH + n];
    unsigned short h = f2bf(x);
    w1fh[e] = h;
    w1fl[e] = f2bf(x - bf2f(h));
}

// W2 [256][40] -> padded N=48 fragment order: e = ((ks*48+n)*4+kq)*8+j3
__global__ void w2pack_kernel(const float* __restrict__ W2,
                              unsigned short* __restrict__ w2fh,
                              unsigned short* __restrict__ w2fl) {
    int e = blockIdx.x * 256 + threadIdx.x;           // 12288 total
    int j3 = e & 7, kq = (e >> 3) & 3;
    int t = e >> 5;
    int n = t % 48, ks = t / 48;
    int k = ks * 32 + kq * 8 + j3;
    float x = (n < NC) ? W2[k * NC + n] : 0.f;
    unsigned short h = f2bf(x);
    w2fh[e] = h;
    w2fl[e] = f2bf(x - bf2f(h));
}

// ---------------------------------------------------------------------------
// Main fused kernel: one block per batch, 256 threads (4 waves).
// LDS (45760 B, phase-aliased):
//   phase A: Xhi [22][520]bf16 @0 (22880 B), Xlo @22880
//   phase B: Hhi [22][264]bf16 @0 (11616 B), Hlo @11616,
//            Sc[840]f32 @23232, pooledD[512]f64 @26592, Dbuf[256]f64 @30688,
//            Sd[40]f64 @32736, SFd[20]f64 @33056
// ---------------------------------------------------------------------------
__global__ __launch_bounds__(256) void fused_kernel(
    const float* __restrict__ F0, const float* __restrict__ V0,
    const float* __restrict__ W1, const float* __restrict__ b1,
    const float* __restrict__ W2, const float* __restrict__ b2,
    const unsigned short* __restrict__ w1fh, const unsigned short* __restrict__ w1fl,
    const unsigned short* __restrict__ w2fh, const unsigned short* __restrict__ w2fl,
    float* __restrict__ outF, float* __restrict__ outS, float* __restrict__ outV)
{
    const int b = blockIdx.x;
    const int j = threadIdx.x;

    __shared__ __align__(16) char lds[45760];
    __shared__ int idx8[SV];
    __shared__ int flags[2];
    __shared__ int predSh;

    unsigned short* Xhi = (unsigned short*)lds;
    unsigned short* Xlo = (unsigned short*)(lds + 22880);
    unsigned short* Hhi = (unsigned short*)lds;
    unsigned short* Hlo = (unsigned short*)(lds + 11616);
    float*  Sc      = (float*)(lds + 23232);
    double* pooledD = (double*)(lds + 26592);
    double* Dbuf    = (double*)(lds + 30688);
    double* Sd      = (double*)(lds + 32736);
    double* SFd     = (double*)(lds + 33056);

    const float* Xb = F0 + (size_t)b * (NV * CC);

    // ---- stage X rows 0..19 as bf16 hi/lo (row stride 520 bf16) ------------
    {
        const float4* src = (const float4*)Xb;
        for (int t = j; t < NV * (CC / 4); t += 256) {
            int r = t >> 7, v = t & 127;
            float4 x = src[t];
            int base = r * 520 + v * 4;
            ushort4v hv, lv;
            hv.x = f2bf(x.x); lv.x = f2bf(x.x - bf2f(hv.x));
            hv.y = f2bf(x.y); lv.y = f2bf(x.y - bf2f(hv.y));
            hv.z = f2bf(x.z); lv.z = f2bf(x.z - bf2f(hv.z));
            hv.w = f2bf(x.w); lv.w = f2bf(x.w - bf2f(hv.w));
            *(ushort4v*)&Xhi[base] = hv;
            *(ushort4v*)&Xlo[base] = lv;
        }
    }
    // zero row 21 of Xhi/Xlo (1040 B each = 130 u64)
    if (j < 130) {
        *(uint64_t*)(lds + 21 * 1040 + j * 8) = 0ull;
        *(uint64_t*)(lds + 22880 + 21 * 1040 + j * 8) = 0ull;
    }
    // pooled row 20 (f32 mean, then hi/lo split)
    for (int c = j; c < CC; c += 256) {
        float s = 0.f;
#pragma unroll
        for (int r = 0; r < NV; ++r) s += Xb[r * CC + c];
        s *= (1.0f / NV);
        unsigned short h = f2bf(s);
        Xhi[20 * 520 + c] = h;
        Xlo[20 * 520 + c] = f2bf(s - bf2f(h));
    }
    __syncthreads();

    // ---- layer 1: H[21][256] via split-bf16 MFMA ---------------------------
    const int L = j & 63, wq = j >> 6, l15 = L & 15, kq = L >> 4;
    const int nb = wq * 64;

    f32x4 acc[2][4];
#pragma unroll
    for (int mt = 0; mt < 2; ++mt)
#pragma unroll
        for (int nt = 0; nt < 4; ++nt) acc[mt][nt] = (f32x4){0.f, 0.f, 0.f, 0.f};

    {
        const uint4* Xh4 = (const uint4*)Xhi;
        const uint4* Xl4 = (const uint4*)Xlo;
        const uint4* Bh = (const uint4*)w1fh;
        const uint4* Bl = (const uint4*)w1fl;
        int am0 = l15;
        int am1 = 16 + l15; if (am1 > 21) am1 = 21;

        uint4 bh[4], bl[4];
#pragma unroll
        for (int nt = 0; nt < 4; ++nt) {
            int bi = (nb + nt * 16 + l15) * 4 + kq;
            bh[nt] = Bh[bi]; bl[nt] = Bl[bi];
        }
        for (int ks = 0; ks < 16; ++ks) {
            uint4 nbh[4], nbl[4];
            int ksn = (ks + 1 < 16) ? ks + 1 : ks;
#pragma unroll
            for (int nt = 0; nt < 4; ++nt) {
                int bi = (ksn * 256 + nb + nt * 16 + l15) * 4 + kq;
                nbh[nt] = Bh[bi]; nbl[nt] = Bl[bi];
            }
            uint4 a0h = Xh4[am0 * 65 + ks * 4 + kq];
            uint4 a0l = Xl4[am0 * 65 + ks * 4 + kq];
            uint4 a1h = Xh4[am1 * 65 + ks * 4 + kq];
            uint4 a1l = Xl4[am1 * 65 + ks * 4 + kq];
            short8 A0h = BC8(a0h), A0l = BC8(a0l), A1h = BC8(a1h), A1l = BC8(a1l);
#pragma unroll
            for (int nt = 0; nt < 4; ++nt) {
                short8 Bhv = BC8(bh[nt]), Blv = BC8(bl[nt]);
                acc[0][nt] = MFMA16(A0h, Bhv, acc[0][nt]);
                acc[0][nt] = MFMA16(A0h, Blv, acc[0][nt]);
                acc[0][nt] = MFMA16(A0l, Bhv, acc[0][nt]);
                acc[1][nt] = MFMA16(A1h, Bhv, acc[1][nt]);
                acc[1][nt] = MFMA16(A1h, Blv, acc[1][nt]);
                acc[1][nt] = MFMA16(A1l, Bhv, acc[1][nt]);
            }
#pragma unroll
            for (int nt = 0; nt < 4; ++nt) { bh[nt] = nbh[nt]; bl[nt] = nbl[nt]; }
        }
    }
    __syncthreads();   // all waves done reading Xhi/Xlo

    // ---- bias + LeakyReLU, write H fragments (hi/lo, stride 264) -----------
#pragma unroll
    for (int mt = 0; mt < 2; ++mt)
#pragma unroll
        for (int nt = 0; nt < 4; ++nt) {
            int col = nb + nt * 16 + l15;
            float bc = b1[col];
#pragma unroll
            for (int reg = 0; reg < 4; ++reg) {
                int r = mt * 16 + kq * 4 + reg;
                if (r < 21) {
                    float h = acc[mt][nt][reg] + bc;
                    h = (h > 0.f) ? h : 0.2f * h;
                    unsigned short hh = f2bf(h);
                    Hhi[r * 264 + col] = hh;
                    Hlo[r * 264 + col] = f2bf(h - bf2f(hh));
                }
            }
        }
    // zero H row 21 (528 B each = 66 u64)
    if (j < 66) {
        *(uint64_t*)(lds + 21 * 528 + j * 8) = 0ull;
        *(uint64_t*)(lds + 11616 + 21 * 528 + j * 8) = 0ull;
    }
    __syncthreads();

    // ---- layer 2: Sc[21][40] via split-bf16 MFMA (waves 0..2) --------------
    if (wq < 3) {
        const uint4* Hh4 = (const uint4*)Hhi;
        const uint4* Hl4 = (const uint4*)Hlo;
        const uint4* B2h = (const uint4*)w2fh;
        const uint4* B2l = (const uint4*)w2fl;
        int hm0 = l15;
        int hm1 = 16 + l15; if (hm1 > 21) hm1 = 21;
        f32x4 sacc[2];
        sacc[0] = (f32x4){0.f, 0.f, 0.f, 0.f};
        sacc[1] = (f32x4){0.f, 0.f, 0.f, 0.f};
        for (int ks = 0; ks < 8; ++ks) {
            int bi = (ks * 48 + wq * 16 + l15) * 4 + kq;
            short8 Bhv = BC8(B2h[bi]), Blv = BC8(B2l[bi]);
            short8 A0h = BC8(Hh4[hm0 * 33 + ks * 4 + kq]);
            short8 A0l = BC8(Hl4[hm0 * 33 + ks * 4 + kq]);
            short8 A1h = BC8(Hh4[hm1 * 33 + ks * 4 + kq]);
            short8 A1l = BC8(Hl4[hm1 * 33 + ks * 4 + kq]);
            sacc[0] = MFMA16(A0h, Bhv, sacc[0]);
            sacc[0] = MFMA16(A0h, Blv, sacc[0]);
            sacc[0] = MFMA16(A0l, Bhv, sacc[0]);
            sacc[1] = MFMA16(A1h, Bhv, sacc[1]);
            sacc[1] = MFMA16(A1h, Blv, sacc[1]);
            sacc[1] = MFMA16(A1l, Bhv, sacc[1]);
        }
        int cls = wq * 16 + l15;
        if (cls < NC) {
            float bc2 = b2[cls];
#pragma unroll
            for (int mt = 0; mt < 2; ++mt)
#pragma unroll
                for (int reg = 0; reg < 4; ++reg) {
                    int r = mt * 16 + kq * 4 + reg;
                    if (r < 21) Sc[r * NC + cls] = sacc[mt][reg] + bc2;
                }
        }
    }
    __syncthreads();

    // ---- pred = argmax of pooled scores (+gap check) -----------------------
    if (j == 0) {
        const float* sp = &Sc[NV * NC];
        int p = 0;
        float m1 = sp[0];
        for (int c = 1; c < NC; ++c)
            if (sp[c] > m1) { m1 = sp[c]; p = c; }
        float m2 = -1e30f;
        for (int c = 0; c < NC; ++c)
            if (c != p && sp[c] > m2) m2 = sp[c];
        flags[0] = (m1 - m2 < TAU) ? 1 : 0;
        predSh = p;
    }
    __syncthreads();

    if (flags[0]) {  // rare: f64 rescore of pooled row
        for (int c = j; c < CC; c += 256) {
            double s = 0.0;
            for (int r = 0; r < NV; ++r) s += (double)Xb[r * CC + c];
            pooledD[c] = s / (double)NV;
        }
        __syncthreads();
        double a = 0.0;
        for (int c = 0; c < CC; ++c) a += pooledD[c] * (double)W1[c * HH + j];
        double h = a + (double)b1[j];
        h = (h > 0.0) ? h : 0.2 * h;
        Dbuf[j] = h;
        __syncthreads();
        if (j < NC) {
            double s = 0.0;
            for (int k = 0; k < HH; ++k) s += Dbuf[k] * (double)W2[k * NC + j];
            Sd[j] = s + (double)b2[j];
        }
        __syncthreads();
        if (j == 0) {
            int p = 0;
            double m = Sd[0];
            for (int c = 1; c < NC; ++c)
                if (Sd[c] > m) { m = Sd[c]; p = c; }
            predSh = p;
        }
        __syncthreads();
    }

    // ---- top-8 selection on score_F (+gap check) ---------------------------
    if (j == 0) {
        int p = predSh;
        float v[NV];
#pragma unroll
        for (int n = 0; n < NV; ++n) v[n] = Sc[n * NC + p];
        int ord[9];
        float vals[9];
        unsigned taken = 0;
#pragma unroll
        for (int s = 0; s < 9; ++s) {
            int bi = 0;
            float bv = -1e30f;
#pragma unroll
            for (int n = 0; n < NV; ++n)
                if (!((taken >> n) & 1u) && v[n] > bv) { bv = v[n]; bi = n; }
            taken |= 1u << bi;
            ord[s] = bi;
            vals[s] = bv;
        }
        int fix = 0;
#pragma unroll
        for (int s = 0; s < 8; ++s)
            if (vals[s] - vals[s + 1] < TAU) fix = 1;
        flags[1] = fix;
        if (!fix)
#pragma unroll
            for (int s = 0; s < SV; ++s) idx8[s] = ord[s];
    }
    __syncthreads();

    if (flags[1]) {  // rare: full f64 rescore of all 20 view scores at column pred
        int p = predSh;
        for (int r = 0; r < NV; ++r) {
            double a = 0.0;
            for (int c = 0; c < CC; ++c)
                a += (double)Xb[r * CC + c] * (double)W1[c * HH + j];
            double h = a + (double)b1[j];
            h = (h > 0.0) ? h : 0.2 * h;
            Dbuf[j] = h * (double)W2[j * NC + p];
            __syncthreads();
            for (int off = 128; off >= 1; off >>= 1) {
                if (j < off) Dbuf[j] += Dbuf[j + off];
                __syncthreads();
            }
            if (j == 0) SFd[r] = Dbuf[0] + (double)b2[p];
            __syncthreads();
        }
        if (j == 0) {
            unsigned taken = 0;
            for (int s = 0; s < SV; ++s) {
                int bi = 0;
                double bv = -1e300;
                for (int n = 0; n < NV; ++n)
                    if (!((taken >> n) & 1u) && SFd[n] > bv) { bv = SFd[n]; bi = n; }
                taken |= 1u << bi;
                idx8[s] = bi;
            }
        }
        __syncthreads();
    }

    // ---- epilogue: score, F_new (float4 gather), vertices ------------------
    for (int t = j; t < NV * NC; t += 256)
        outS[(size_t)b * (NV * NC) + t] = Sc[t];

    for (int qq = j; qq < SV * (CC / 4); qq += 256) {
        int s = qq >> 7;           // CC/4 == 128
        int t4 = qq & 127;
        const float4* src = (const float4*)(Xb + idx8[s] * CC);
        float4* dst = (float4*)(outF + ((size_t)b * SV + s) * CC);
        dst[t4] = src[t4];
    }

    if (j < SV * 3) {
        int s = j / 3;
        int d = j - s * 3;
        outV[((size_t)b * SV + s) * 3 + d] = V0[((size_t)b * NV + idx8[s]) * 3 + d];
    }
}

// ---------------------------------------------------------------------------
extern "C" void kernel_launch(void* const* d_in, const int* in_sizes, int n_in,
                              void* d_out, int out_size, void* d_ws, size_t ws_size,
                              hipStream_t stream) {
    const float* F0 = (const float*)d_in[0];
    const float* V0 = (const float*)d_in[1];
    const float* W1 = (const float*)d_in[2];
    const float* b1 = (const float*)d_in[3];
    const float* W2 = (const float*)d_in[4];
    const float* b2 = (const float*)d_in[5];

    char* ws = (char*)d_ws;
    unsigned short* w1fh = (unsigned short*)ws;                   // 262144 B
    unsigned short* w1fl = (unsigned short*)(ws + 262144);        // 262144 B
    unsigned short* w2fh = (unsigned short*)(ws + 524288);        // 24576 B
    unsigned short* w2fl = (unsigned short*)(ws + 548864);        // 24576 B

    float* out = (float*)d_out;
    float* outF = out;                                // [4096,8,512]
    float* outS = out + (size_t)BB * SV * CC;         // [4096,20,40]
    float* outV = outS + (size_t)BB * NV * NC;        // [4096,8,3]

    w1pack_kernel<<<512, 256, 0, stream>>>(W1, w1fh, w1fl);
    w2pack_kernel<<<48, 256, 0, stream>>>(W2, w2fh, w2fl);
    fused_kernel<<<BB, 256, 0, stream>>>(F0, V0, W1, b1, W2, b2,
                                         w1fh, w1fl, w2fh, w2fl,
                                         outF, outS, outV);
}

// Round 5
// 723.060 us; speedup vs baseline: 1.7151x; 1.1459x over previous
//
#include <hip/hip_runtime.h>
#include <cstdint>

#define BB 4096
#define NV 20
#define CC 512
#define HH 256   // hidden
#define NC 40    // classes
#define SV 8     // selected views
#define GG 3     // batches per block
#define TAU 2e-4f

typedef short short8 __attribute__((ext_vector_type(8)));
typedef float f32x4 __attribute__((ext_vector_type(4)));
typedef unsigned short ushort4v __attribute__((ext_vector_type(4)));

__device__ __forceinline__ unsigned short f2bf(float x) {
    unsigned u = __float_as_uint(x);
    unsigned r = (u + 0x7FFFu + ((u >> 16) & 1u)) >> 16;
    return (unsigned short)r;
}
__device__ __forceinline__ float bf2f(unsigned short h) {
    return __uint_as_float(((unsigned)h) << 16);
}

#define MFMA16(A, B, C) __builtin_amdgcn_mfma_f32_16x16x32_bf16(A, B, C, 0, 0, 0)
#define BC8(x) __builtin_bit_cast(short8, x)

// ---------------------------------------------------------------------------
// W1 [512][256] -> fragment-ordered bf16 hi/lo (same layout as R4, verified):
//   e = ((ks*256 + n)*4 + kq)*8 + j3 ; k = ks*32 + kq*8 + j3
// ---------------------------------------------------------------------------
__global__ void w1pack_kernel(const float* __restrict__ W1,
                              unsigned short* __restrict__ w1fh,
                              unsigned short* __restrict__ w1fl) {
    int e = blockIdx.x * 256 + threadIdx.x;           // 131072 total
    int j3 = e & 7, kq = (e >> 3) & 3, n = (e >> 5) & 255, ks = e >> 13;
    int k = ks * 32 + kq * 8 + j3;
    float x = W1[k * HH + n];
    unsigned short h = f2bf(x);
    w1fh[e] = h;
    w1fl[e] = f2bf(x - bf2f(h));
}

// W2 [256][40] -> padded N=48 fragment order: e = ((ks*48+n)*4+kq)*8+j3
__global__ void w2pack_kernel(const float* __restrict__ W2,
                              unsigned short* __restrict__ w2fh,
                              unsigned short* __restrict__ w2fl) {
    int e = blockIdx.x * 256 + threadIdx.x;           // 12288 total
    int j3 = e & 7, kq = (e >> 3) & 3;
    int t = e >> 5;
    int n = t % 48, ks = t / 48;
    int k = ks * 32 + kq * 8 + j3;
    float x = (n < NC) ? W2[k * NC + n] : 0.f;
    unsigned short h = f2bf(x);
    w2fh[e] = h;
    w2fl[e] = f2bf(x - bf2f(h));
}

// ---------------------------------------------------------------------------
// Fused kernel: one block per GG=3 batches (M=64 tile: 63 rows + 1 pad).
// LDS phases (aliased):
//   phase1: Ahi[64][72]bf16 @0 (9216B), Alo @9216           (K-chunk staging)
//   phase2: Hhi[32][264]bf16 @0 (16896B), Hlo @16896        (layer-2 rounds)
//   phase3: pooledD[512]f64 @0, Dbuf[256]f64 @4096, Sd @6144, SFd @6464
//   persistent: Sc[3][840]f32 @33792 (ends 43872)
// ---------------------------------------------------------------------------
__global__ __launch_bounds__(256, 3) void fused_kernel(
    const float* __restrict__ F0, const float* __restrict__ V0,
    const float* __restrict__ W1, const float* __restrict__ b1,
    const float* __restrict__ W2, const float* __restrict__ b2,
    const unsigned short* __restrict__ w1fh, const unsigned short* __restrict__ w1fl,
    const unsigned short* __restrict__ w2fh, const unsigned short* __restrict__ w2fl,
    float* __restrict__ outF, float* __restrict__ outS, float* __restrict__ outV)
{
    const int blk = blockIdx.x;
    const int j = threadIdx.x;
    const int L = j & 63, wq = j >> 6, l15 = L & 15, kq = L >> 4;

    __shared__ __align__(16) char lds[43872];
    __shared__ int idx8[GG][SV];
    __shared__ int flags0[GG], flags1[GG], predS[GG];

    unsigned short* Ahi = (unsigned short*)lds;            // [64][72]
    unsigned short* Alo = Ahi + 64 * 72;                   // @9216 B
    unsigned short* Hhi = (unsigned short*)lds;            // [32][264]
    unsigned short* Hlo = Hhi + 32 * 264;                  // @16896 B
    float*  Sc      = (float*)(lds + 33792);               // 3*840 f32
    double* pooledD = (double*)lds;
    double* Dbuf    = (double*)(lds + 4096);
    double* Sd      = (double*)(lds + 6144);
    double* SFd     = (double*)(lds + 6464);

    // ---- layer-1 accumulators: acc[mt][nt], rows mt*16+kq*4+reg, col wq*64+nt*16+l15
    f32x4 acc[4][4];
#pragma unroll
    for (int mt = 0; mt < 4; ++mt)
#pragma unroll
        for (int nt = 0; nt < 4; ++nt) acc[mt][nt] = (f32x4){0.f, 0.f, 0.f, 0.f};

    const uint4* Bh = (const uint4*)w1fh;
    const uint4* Bl = (const uint4*)w1fl;

    // ---- K-loop: 8 chunks of Kc=64 ----------------------------------------
    for (int kc = 0; kc < 8; ++kc) {
        __syncthreads();   // A region free (prev chunk's reads done)

        // stage 64 rows x 64 cols f32 -> bf16 hi/lo LDS
#pragma unroll
        for (int i = 0; i < 4; ++i) {
            int f = j + 256 * i;          // float4 index in chunk [0,1024)
            int row = f >> 4, k4 = f & 15;
            int bi = row / 21, r = row - bi * 21;
            ushort4v hv = {0, 0, 0, 0}, lv = {0, 0, 0, 0};
            if (row < 63 && r < NV) {
                int batch = blk * GG + bi; if (batch > BB - 1) batch = BB - 1;
                float4 x = *(const float4*)(F0 + ((size_t)batch * NV + r) * CC + kc * 64 + k4 * 4);
                hv.x = f2bf(x.x); lv.x = f2bf(x.x - bf2f(hv.x));
                hv.y = f2bf(x.y); lv.y = f2bf(x.y - bf2f(hv.y));
                hv.z = f2bf(x.z); lv.z = f2bf(x.z - bf2f(hv.z));
                hv.w = f2bf(x.w); lv.w = f2bf(x.w - bf2f(hv.w));
            }
            *(ushort4v*)&Ahi[row * 72 + k4 * 4] = hv;
            *(ushort4v*)&Alo[row * 72 + k4 * 4] = lv;
        }
        __syncthreads();

        // pooled rows (r=20 per batch) for this K-chunk, from hi+lo
        if (j < 192) {
            int bi = j >> 6, kk = j & 63;
            float s = 0.f;
#pragma unroll
            for (int r = 0; r < NV; ++r) {
                int idx = (bi * 21 + r) * 72 + kk;
                s += bf2f(Ahi[idx]) + bf2f(Alo[idx]);
            }
            s *= (1.0f / NV);
            unsigned short h = f2bf(s);
            Ahi[(bi * 21 + 20) * 72 + kk] = h;
            Alo[(bi * 21 + 20) * 72 + kk] = f2bf(s - bf2f(h));
        }
        __syncthreads();

        // MFMA: 2 global k-steps per chunk
#pragma unroll
        for (int ks_l = 0; ks_l < 2; ++ks_l) {
            int ks = kc * 2 + ks_l;
            uint4 bh[4], bl[4];
#pragma unroll
            for (int nt = 0; nt < 4; ++nt) {
                int bi1 = (ks * 256 + wq * 64 + nt * 16 + l15) * 4 + kq;
                bh[nt] = Bh[bi1]; bl[nt] = Bl[bi1];
            }
            uint4 ah[4], al[4];
#pragma unroll
            for (int mt = 0; mt < 4; ++mt) {
                int off = (mt * 16 + l15) * 72 + ks_l * 32 + kq * 8;  // ushort units
                ah[mt] = *(const uint4*)&Ahi[off];
                al[mt] = *(const uint4*)&Alo[off];
            }
#pragma unroll
            for (int mt = 0; mt < 4; ++mt) {
                short8 Ah = BC8(ah[mt]), Al = BC8(al[mt]);
#pragma unroll
                for (int nt = 0; nt < 4; ++nt) {
                    short8 Bhv = BC8(bh[nt]), Blv = BC8(bl[nt]);
                    acc[mt][nt] = MFMA16(Ah, Bhv, acc[mt][nt]);
                    acc[mt][nt] = MFMA16(Ah, Blv, acc[mt][nt]);
                    acc[mt][nt] = MFMA16(Al, Bhv, acc[mt][nt]);
                }
            }
        }
    }

    // ---- layer 2: two rounds of 2 M-tiles (32 rows) through LDS ------------
    const uint4* B2h = (const uint4*)w2fh;
    const uint4* B2l = (const uint4*)w2fl;
#pragma unroll
    for (int p = 0; p < 2; ++p) {
        __syncthreads();   // Hbuf region free (A reads / prev round reads done)
#pragma unroll
        for (int mt2 = 0; mt2 < 2; ++mt2) {
            int mt = 2 * p + mt2;
#pragma unroll
            for (int nt = 0; nt < 4; ++nt) {
                int col = wq * 64 + nt * 16 + l15;
                float bc = b1[col];
#pragma unroll
                for (int reg = 0; reg < 4; ++reg) {
                    int hb = mt2 * 16 + kq * 4 + reg;
                    float h = acc[mt][nt][reg] + bc;
                    h = (h > 0.f) ? h : 0.2f * h;
                    unsigned short hh = f2bf(h);
                    Hhi[hb * 264 + col] = hh;
                    Hlo[hb * 264 + col] = f2bf(h - bf2f(hh));
                }
            }
        }
        __syncthreads();

        if (wq < 3) {
            f32x4 sacc[2];
            sacc[0] = (f32x4){0.f, 0.f, 0.f, 0.f};
            sacc[1] = (f32x4){0.f, 0.f, 0.f, 0.f};
            for (int ks2 = 0; ks2 < 8; ++ks2) {
                int bi2 = (ks2 * 48 + wq * 16 + l15) * 4 + kq;
                short8 Bhv = BC8(B2h[bi2]), Blv = BC8(B2l[bi2]);
#pragma unroll
                for (int tt = 0; tt < 2; ++tt) {
                    int off = (tt * 16 + l15) * 264 + ks2 * 32 + kq * 8;
                    short8 Ah = BC8(*(const uint4*)&Hhi[off]);
                    short8 Al = BC8(*(const uint4*)&Hlo[off]);
                    sacc[tt] = MFMA16(Ah, Bhv, sacc[tt]);
                    sacc[tt] = MFMA16(Ah, Blv, sacc[tt]);
                    sacc[tt] = MFMA16(Al, Bhv, sacc[tt]);
                }
            }
            int cls = wq * 16 + l15;
            if (cls < NC) {
                float bc2 = b2[cls];
#pragma unroll
                for (int tt = 0; tt < 2; ++tt)
#pragma unroll
                    for (int reg = 0; reg < 4; ++reg) {
                        int lm = 32 * p + tt * 16 + kq * 4 + reg;
                        if (lm < 63) {
                            int bi = lm / 21, r = lm - bi * 21;
                            Sc[bi * 840 + r * NC + cls] = sacc[tt][reg] + bc2;
                        }
                    }
            }
        }
    }
    __syncthreads();

    // ---- decisions: pred argmax (3 parallel lanes, gap-guarded) ------------
    if (j < GG) {
        const float* sp = &Sc[j * 840 + NV * NC];
        int p = 0;
        float m1 = sp[0];
        for (int c = 1; c < NC; ++c)
            if (sp[c] > m1) { m1 = sp[c]; p = c; }
        float m2 = -1e30f;
        for (int c = 0; c < NC; ++c)
            if (c != p && sp[c] > m2) m2 = sp[c];
        flags0[j] = (m1 - m2 < TAU) ? 1 : 0;
        predS[j] = p;
    }
    __syncthreads();

    for (int bi = 0; bi < GG; ++bi) {
        if (flags0[bi]) {   // rare: f64 rescore of pooled row
            int batch = blk * GG + bi; if (batch > BB - 1) batch = BB - 1;
            const float* Xb = F0 + (size_t)batch * (NV * CC);
            for (int c = j; c < CC; c += 256) {
                double s = 0.0;
                for (int r = 0; r < NV; ++r) s += (double)Xb[r * CC + c];
                pooledD[c] = s / (double)NV;
            }
            __syncthreads();
            double a = 0.0;
            for (int c = 0; c < CC; ++c) a += pooledD[c] * (double)W1[c * HH + j];
            double h = a + (double)b1[j];
            h = (h > 0.0) ? h : 0.2 * h;
            Dbuf[j] = h;
            __syncthreads();
            if (j < NC) {
                double s = 0.0;
                for (int k = 0; k < HH; ++k) s += Dbuf[k] * (double)W2[k * NC + j];
                Sd[j] = s + (double)b2[j];
            }
            __syncthreads();
            if (j == 0) {
                int p = 0;
                double m = Sd[0];
                for (int c = 1; c < NC; ++c)
                    if (Sd[c] > m) { m = Sd[c]; p = c; }
                predS[bi] = p;
            }
            __syncthreads();
        }
    }

    // ---- top-8 selection (3 parallel lanes, gap-guarded) -------------------
    if (j < GG) {
        int p = predS[j];
        float v[NV];
#pragma unroll
        for (int n = 0; n < NV; ++n) v[n] = Sc[j * 840 + n * NC + p];
        int ord[9];
        float vals[9];
        unsigned taken = 0;
#pragma unroll
        for (int s = 0; s < 9; ++s) {
            int bi = 0;
            float bv = -1e30f;
#pragma unroll
            for (int n = 0; n < NV; ++n)
                if (!((taken >> n) & 1u) && v[n] > bv) { bv = v[n]; bi = n; }
            taken |= 1u << bi;
            ord[s] = bi;
            vals[s] = bv;
        }
        int fix = 0;
#pragma unroll
        for (int s = 0; s < 8; ++s)
            if (vals[s] - vals[s + 1] < TAU) fix = 1;
        flags1[j] = fix;
        if (!fix)
#pragma unroll
            for (int s = 0; s < SV; ++s) idx8[j][s] = ord[s];
    }
    __syncthreads();

    for (int bi = 0; bi < GG; ++bi) {
        if (flags1[bi]) {   // rare: full f64 rescore of 20 view scores at col pred
            int batch = blk * GG + bi; if (batch > BB - 1) batch = BB - 1;
            const float* Xb = F0 + (size_t)batch * (NV * CC);
            int p = predS[bi];
            for (int r = 0; r < NV; ++r) {
                double a = 0.0;
                for (int c = 0; c < CC; ++c)
                    a += (double)Xb[r * CC + c] * (double)W1[c * HH + j];
                double h = a + (double)b1[j];
                h = (h > 0.0) ? h : 0.2 * h;
                Dbuf[j] = h * (double)W2[j * NC + p];
                __syncthreads();
                for (int off = 128; off >= 1; off >>= 1) {
                    if (j < off) Dbuf[j] += Dbuf[j + off];
                    __syncthreads();
                }
                if (j == 0) SFd[r] = Dbuf[0] + (double)b2[p];
                __syncthreads();
            }
            if (j == 0) {
                unsigned taken = 0;
                for (int s = 0; s < SV; ++s) {
                    int bsel = 0;
                    double bv = -1e300;
                    for (int n = 0; n < NV; ++n)
                        if (!((taken >> n) & 1u) && SFd[n] > bv) { bv = SFd[n]; bsel = n; }
                    taken |= 1u << bsel;
                    idx8[bi][s] = bsel;
                }
            }
            __syncthreads();
        }
    }

    // ---- epilogue -----------------------------------------------------------
    for (int t = j; t < GG * NV * NC; t += 256) {
        int bi = t / 800, o = t - bi * 800;
        int batch = blk * GG + bi; if (batch > BB - 1) batch = BB - 1;
        outS[(size_t)batch * (NV * NC) + o] = Sc[bi * 840 + o];
    }

    for (int t = j; t < GG * SV * (CC / 4); t += 256) {
        int bi = t >> 10;                 // /1024
        int s = (t >> 7) & 7;
        int t4 = t & 127;
        int batch = blk * GG + bi; if (batch > BB - 1) batch = BB - 1;
        int row = idx8[bi][s];
        const float4* src = (const float4*)(F0 + ((size_t)batch * NV + row) * CC);
        float4* dst = (float4*)(outF + ((size_t)batch * SV + s) * CC);
        dst[t4] = src[t4];
    }

    if (j < GG * SV * 3) {
        int bi = j / 24, o = j - bi * 24;
        int s = o / 3, d = o - s * 3;
        int batch = blk * GG + bi; if (batch > BB - 1) batch = BB - 1;
        outV[((size_t)batch * SV + s) * 3 + d] =
            V0[((size_t)batch * NV + idx8[bi][s]) * 3 + d];
    }
}

// ---------------------------------------------------------------------------
extern "C" void kernel_launch(void* const* d_in, const int* in_sizes, int n_in,
                              void* d_out, int out_size, void* d_ws, size_t ws_size,
                              hipStream_t stream) {
    const float* F0 = (const float*)d_in[0];
    const float* V0 = (const float*)d_in[1];
    const float* W1 = (const float*)d_in[2];
    const float* b1 = (const float*)d_in[3];
    const float* W2 = (const float*)d_in[4];
    const float* b2 = (const float*)d_in[5];

    char* ws = (char*)d_ws;
    unsigned short* w1fh = (unsigned short*)ws;                   // 262144 B
    unsigned short* w1fl = (unsigned short*)(ws + 262144);        // 262144 B
    unsigned short* w2fh = (unsigned short*)(ws + 524288);        // 24576 B
    unsigned short* w2fl = (unsigned short*)(ws + 548864);        // 24576 B

    float* out = (float*)d_out;
    float* outF = out;                                // [4096,8,512]
    float* outS = out + (size_t)BB * SV * CC;         // [4096,20,40]
    float* outV = outS + (size_t)BB * NV * NC;        // [4096,8,3]

    w1pack_kernel<<<512, 256, 0, stream>>>(W1, w1fh, w1fl);
    w2pack_kernel<<<48, 256, 0, stream>>>(W2, w2fh, w2fl);
    fused_kernel<<<(BB + GG - 1) / GG, 256, 0, stream>>>(
        F0, V0, W1, b1, W2, b2, w1fh, w1fl, w2fh, w2fl, outF, outS, outV);
}